// Round 16
// baseline (35.521 us; speedup 1.0000x reference)
//
#include <hip/hip_runtime.h>

#define BATCH 512
#define PIX   65536
#define NOUT  512
#define COUT  4
#define NCLS  10

#define KC    4096                // K-chunk (pixels) per gemm block
#define NKC   (PIX / KC)          // 16
#define NRG   (BATCH / 8)         // 64 row-groups (8 rows per block)

// must match __builtin_amdgcn_cvt_pkrtz's return type exactly
typedef __fp16 half2_t __attribute__((ext_vector_type(2)));

#if __has_builtin(__builtin_amdgcn_fdot2)
__device__ __forceinline__ float fdot2f(half2_t a, half2_t b, float c) {
    return __builtin_amdgcn_fdot2(a, b, c, false);
}
#else
__device__ __forceinline__ float fdot2f(half2_t a, half2_t b, float c) {
    return c + (float)a[0] * (float)b[0] + (float)a[1] * (float)b[1];
}
#endif

// ---------------------------------------------------------------------------
// 0: build AwT[k][p] (f16, [10][65536]) = Weff[seg[p]][k].
// 256 blocks; W_fc staged into LDS with coalesced float4 loads; Weff computed
// redundantly from LDS; each block pair-packs a 256-pixel window. Block 0
// additionally computes cst and inits out = cst.  (R15 version, unchanged.)
// ---------------------------------------------------------------------------
__global__ __launch_bounds__(256) void awbuild_kernel(
    const float* __restrict__ W_fgl, const float* __restrict__ b_fgl,
    const float* __restrict__ W_fc,  const float* __restrict__ b_fc,
    const int* __restrict__ seg, unsigned* __restrict__ AwT32,
    float* __restrict__ out)
{
    __shared__ float    wfc[NOUT * COUT * NCLS];          // 81920 B
    __shared__ unsigned wh[NOUT * 5];                     // 10240 B
    __shared__ float    red[4 * NCLS];
    __shared__ float    cs[NCLS];

    const int t = threadIdx.x, bid = blockIdx.x;

    const float4* wf4 = (const float4*)W_fc;
    float4* lf4 = (float4*)wfc;
#pragma unroll
    for (int i = 0; i < 20; ++i) lf4[i * 256 + t] = wf4[i * 256 + t];
    __syncthreads();

    float cpart[NCLS];
#pragma unroll
    for (int k = 0; k < NCLS; ++k) cpart[k] = 0.f;

#pragma unroll
    for (int jj = 0; jj < 2; ++jj) {
        const int j = jj * 256 + t;
        float wf[COUT], bf[COUT];
#pragma unroll
        for (int c = 0; c < COUT; ++c) {
            wf[c] = W_fgl[c * NOUT + j];
            bf[c] = b_fgl[c * NOUT + j];
        }
        float wv[NCLS];
#pragma unroll
        for (int k = 0; k < NCLS; ++k) {
            float w = 0.f, cb = 0.f;
#pragma unroll
            for (int c = 0; c < COUT; ++c) {
                const float wfc_v = wfc[(c * NOUT + j) * NCLS + k];
                w  += wf[c] * wfc_v;
                cb += bf[c] * wfc_v;
            }
            wv[k] = w;
            cpart[k] += cb;
        }
#pragma unroll
        for (int k5 = 0; k5 < 5; ++k5) {
            const half2_t h = __builtin_amdgcn_cvt_pkrtz(wv[2 * k5], wv[2 * k5 + 1]);
            wh[j * 5 + k5] = __builtin_bit_cast(unsigned, h);
        }
    }
    __syncthreads();

    if (t < 128) {
        const int pp = bid * 128 + t;
        const int2 js = *(const int2*)(seg + pp * 2);
        const unsigned* wa = &wh[js.x * 5];
        const unsigned* wb = &wh[js.y * 5];
#pragma unroll
        for (int k5 = 0; k5 < 5; ++k5) {
            const unsigned a = wa[k5], b = wb[k5];
            AwT32[(2 * k5)     * (PIX / 2) + pp] = (a & 0xffffu) | (b << 16);
            AwT32[(2 * k5 + 1) * (PIX / 2) + pp] = (a >> 16) | (b & 0xffff0000u);
        }
    }

    if (bid == 0) {
#pragma unroll
        for (int k = 0; k < NCLS; ++k)
#pragma unroll
            for (int off = 32; off; off >>= 1)
                cpart[k] += __shfl_down(cpart[k], off);
        if ((t & 63) == 0) {
#pragma unroll
            for (int k = 0; k < NCLS; ++k) red[(t >> 6) * NCLS + k] = cpart[k];
        }
        __syncthreads();
        if (t < NCLS) {
            float s = b_fc[t];
#pragma unroll
            for (int w2 = 0; w2 < 4; ++w2) s += red[w2 * NCLS + t];
            cs[t] = s;
        }
        __syncthreads();
        for (int i = t; i < BATCH * NCLS; i += 256) out[i] = cs[i % NCLS];
    }
}

// ---------------------------------------------------------------------------
// 1: GEMM: out[n,k] += sum_p x[n,p] * AwT[k][p]
// Block = 8 rows x 4096-px chunk; grid = 64 rowg x 16 kc = 1024 = EXACTLY
// 4 blocks/CU, all co-resident (zero LDS) -> no mid-kernel block boundaries.
// Epilogue: 64-lane butterfly shuffle reduce + ONE wave-wide atomic instr
// (20 active lanes) -> no __syncthreads, no LDS, no partial-wave tail.
// ---------------------------------------------------------------------------
__global__ __launch_bounds__(256, 4) void gemm_kernel(
    const float* __restrict__ x, const unsigned short* __restrict__ AwT,
    float* __restrict__ out)
{
    const int t = threadIdx.x, w = t >> 6, lane = t & 63;
    const int rowg = blockIdx.x & (NRG - 1);
    const int kc   = blockIdx.x >> 6;
    const int pc   = kc * KC;
    const int r0   = rowg * 8 + w * 2;

    const float4* __restrict__ xa = (const float4*)(x + (size_t)r0 * PIX + pc);
    const float4* __restrict__ xb = (const float4*)(x + (size_t)(r0 + 1) * PIX + pc);

    float acc0[NCLS] = {}, acc1[NCLS] = {};
#pragma unroll
    for (int i = 0; i < KC / 512; ++i) {             // 8 iterations
        const int e8 = i * 64 + lane;                // 8-pixel group index
        uint4 awq[NCLS];
#pragma unroll
        for (int k = 0; k < NCLS; ++k)
            awq[k] = *(const uint4*)(AwT + (size_t)k * PIX + pc + e8 * 8);
        const float4 va0 = xa[e8 * 2], va1 = xa[e8 * 2 + 1];
        const float4 vb0 = xb[e8 * 2], vb1 = xb[e8 * 2 + 1];
        const half2_t a01 = __builtin_amdgcn_cvt_pkrtz(va0.x, va0.y);
        const half2_t a23 = __builtin_amdgcn_cvt_pkrtz(va0.z, va0.w);
        const half2_t a45 = __builtin_amdgcn_cvt_pkrtz(va1.x, va1.y);
        const half2_t a67 = __builtin_amdgcn_cvt_pkrtz(va1.z, va1.w);
        const half2_t b01 = __builtin_amdgcn_cvt_pkrtz(vb0.x, vb0.y);
        const half2_t b23 = __builtin_amdgcn_cvt_pkrtz(vb0.z, vb0.w);
        const half2_t b45 = __builtin_amdgcn_cvt_pkrtz(vb1.x, vb1.y);
        const half2_t b67 = __builtin_amdgcn_cvt_pkrtz(vb1.z, vb1.w);
#pragma unroll
        for (int k = 0; k < NCLS; ++k) {
            const half2_t w01 = __builtin_bit_cast(half2_t, awq[k].x);
            const half2_t w23 = __builtin_bit_cast(half2_t, awq[k].y);
            const half2_t w45 = __builtin_bit_cast(half2_t, awq[k].z);
            const half2_t w67 = __builtin_bit_cast(half2_t, awq[k].w);
            acc0[k] = fdot2f(a67, w67, fdot2f(a45, w45,
                      fdot2f(a23, w23, fdot2f(a01, w01, acc0[k]))));
            acc1[k] = fdot2f(b67, w67, fdot2f(b45, w45,
                      fdot2f(b23, w23, fdot2f(b01, w01, acc1[k]))));
        }
    }

    // ---- epilogue: butterfly reduce across the wave ----
#pragma unroll
    for (int k = 0; k < NCLS; ++k) {
#pragma unroll
        for (int off = 32; off; off >>= 1) {
            acc0[k] += __shfl_xor(acc0[k], off);
            acc1[k] += __shfl_xor(acc1[k], off);
        }
    }

    // lane k (k<10) carries row r0 value for class k; lane 16+k carries r0+1
    float myv = 0.f;
#pragma unroll
    for (int k = 0; k < NCLS; ++k) {
        myv = (lane == k)      ? acc0[k] : myv;
        myv = (lane == 16 + k) ? acc1[k] : myv;
    }
    if (lane < NCLS || (lane >= 16 && lane < 16 + NCLS)) {
        const int rr = (lane < NCLS) ? r0 : (r0 + 1);
        const int kk = (lane < NCLS) ? lane : (lane - 16);
        unsafeAtomicAdd(&out[rr * NCLS + kk], myv);
    }
}

// ---------------------------------------------------------------------------
extern "C" void kernel_launch(void* const* d_in, const int* in_sizes, int n_in,
                              void* d_out, int out_size, void* d_ws, size_t ws_size,
                              hipStream_t stream)
{
    const float* x     = (const float*)d_in[0];
    const float* W_fgl = (const float*)d_in[1];
    const float* b_fgl = (const float*)d_in[2];
    const float* W_fc  = (const float*)d_in[3];
    const float* b_fc  = (const float*)d_in[4];
    const int*   seg   = (const int*)d_in[5];
    float*       out   = (float*)d_out;

    unsigned* AwT32 = (unsigned*)d_ws;     // AwT [10][65536] f16 = 1.31 MB

    awbuild_kernel<<<dim3(256),        256, 0, stream>>>(
        W_fgl, b_fgl, W_fc, b_fc, seg, AwT32, out);

    gemm_kernel<<<dim3(NRG * NKC), 256, 0, stream>>>(
        x, (const unsigned short*)AwT32, out);
}

// Round 18
// 32.624 us; speedup vs baseline: 1.0888x; 1.0888x over previous
//
#include <hip/hip_runtime.h>

#define BATCH 512
#define PIX   65536
#define NOUT  512
#define COUT  4
#define NCLS  10

#define KC    1024                // K-chunk (pixels) per gemm block (R14 best)
#define NKC   (PIX / KC)          // 64
#define NRG   (BATCH / 8)         // 64 row-groups (8 rows per block)

// must match __builtin_amdgcn_cvt_pkrtz's return type exactly
typedef __fp16 half2_t __attribute__((ext_vector_type(2)));

#if __has_builtin(__builtin_amdgcn_fdot2)
__device__ __forceinline__ float fdot2f(half2_t a, half2_t b, float c) {
    return __builtin_amdgcn_fdot2(a, b, c, false);
}
#else
__device__ __forceinline__ float fdot2f(half2_t a, half2_t b, float c) {
    return c + (float)a[0] * (float)b[0] + (float)a[1] * (float)b[1];
}
#endif

// ---------------------------------------------------------------------------
// 0: build AwT[k][p] (f16, [10][65536]) = Weff[seg[p]][k].
// 256 blocks; W_fc staged into LDS with coalesced float4 loads (R15 version);
// Weff computed redundantly from LDS; each block pair-packs a 256-pixel
// window. Block 0 additionally computes cst and inits out = cst.
// ---------------------------------------------------------------------------
__global__ __launch_bounds__(256) void awbuild_kernel(
    const float* __restrict__ W_fgl, const float* __restrict__ b_fgl,
    const float* __restrict__ W_fc,  const float* __restrict__ b_fc,
    const int* __restrict__ seg, unsigned* __restrict__ AwT32,
    float* __restrict__ out)
{
    __shared__ float    wfc[NOUT * COUT * NCLS];          // 81920 B
    __shared__ unsigned wh[NOUT * 5];                     // 10240 B
    __shared__ float    red[4 * NCLS];
    __shared__ float    cs[NCLS];

    const int t = threadIdx.x, bid = blockIdx.x;

    // ---- stage W_fc coalesced: 5120 float4 ----
    const float4* wf4 = (const float4*)W_fc;
    float4* lf4 = (float4*)wfc;
#pragma unroll
    for (int i = 0; i < 20; ++i) lf4[i * 256 + t] = wf4[i * 256 + t];
    __syncthreads();

    // ---- Weff from LDS (stride-10 dword reads: 2 lanes/bank, free) ----
    float cpart[NCLS];
#pragma unroll
    for (int k = 0; k < NCLS; ++k) cpart[k] = 0.f;

#pragma unroll
    for (int jj = 0; jj < 2; ++jj) {
        const int j = jj * 256 + t;
        float wf[COUT], bf[COUT];
#pragma unroll
        for (int c = 0; c < COUT; ++c) {
            wf[c] = W_fgl[c * NOUT + j];     // coalesced by j
            bf[c] = b_fgl[c * NOUT + j];
        }
        float wv[NCLS];
#pragma unroll
        for (int k = 0; k < NCLS; ++k) {
            float w = 0.f, cb = 0.f;
#pragma unroll
            for (int c = 0; c < COUT; ++c) {
                const float wfc_v = wfc[(c * NOUT + j) * NCLS + k];
                w  += wf[c] * wfc_v;
                cb += bf[c] * wfc_v;
            }
            wv[k] = w;
            cpart[k] += cb;
        }
#pragma unroll
        for (int k5 = 0; k5 < 5; ++k5) {
            const half2_t h = __builtin_amdgcn_cvt_pkrtz(wv[2 * k5], wv[2 * k5 + 1]);
            wh[j * 5 + k5] = __builtin_bit_cast(unsigned, h);
        }
    }
    __syncthreads();

    // ---- pair-pack this block's 256-pixel window (128 pairs) ----
    if (t < 128) {
        const int pp = bid * 128 + t;
        const int2 js = *(const int2*)(seg + pp * 2);
        const unsigned* wa = &wh[js.x * 5];
        const unsigned* wb = &wh[js.y * 5];
#pragma unroll
        for (int k5 = 0; k5 < 5; ++k5) {
            const unsigned a = wa[k5], b = wb[k5];
            AwT32[(2 * k5)     * (PIX / 2) + pp] = (a & 0xffffu) | (b << 16);
            AwT32[(2 * k5 + 1) * (PIX / 2) + pp] = (a >> 16) | (b & 0xffff0000u);
        }
    }

    // ---- block 0: cst + out init ----
    if (bid == 0) {
#pragma unroll
        for (int k = 0; k < NCLS; ++k)
#pragma unroll
            for (int off = 32; off; off >>= 1)
                cpart[k] += __shfl_down(cpart[k], off);
        if ((t & 63) == 0) {
#pragma unroll
            for (int k = 0; k < NCLS; ++k) red[(t >> 6) * NCLS + k] = cpart[k];
        }
        __syncthreads();
        if (t < NCLS) {
            float s = b_fc[t];
#pragma unroll
            for (int w2 = 0; w2 < 4; ++w2) s += red[w2 * NCLS + t];
            cs[t] = s;
        }
        __syncthreads();
        for (int i = t; i < BATCH * NCLS; i += 256) out[i] = cs[i % NCLS];
    }
}

// ---------------------------------------------------------------------------
// 1: GEMM: out[n,k] += sum_p x[n,p] * AwT[k][p]   (R14 version, verbatim)
// Block = 8 rows x 1024-px chunk; grid = 64 rowg x 64 kc (kc-major -> AwT and
// seg chunks L2-hot). NO LDS staging for Aw: uint4 straight from L2. DS pipe
// only carries the final reduce. 2 fully-unrolled inner iterations -> all 28
// VMEM loads in flight before first consume.
// ---------------------------------------------------------------------------
__global__ __launch_bounds__(256, 4) void gemm_kernel(
    const float* __restrict__ x, const unsigned short* __restrict__ AwT,
    float* __restrict__ out)
{
    __shared__ __align__(16) float part[20 * 264];   // 21120 B

    const int t = threadIdx.x, w = t >> 6, lane = t & 63;
    const int rowg = blockIdx.x & (NRG - 1);
    const int kc   = blockIdx.x >> 6;
    const int pc   = kc * KC;
    const int r0   = rowg * 8 + w * 2;

    const float4* __restrict__ xa = (const float4*)(x + (size_t)r0 * PIX + pc);
    const float4* __restrict__ xb = (const float4*)(x + (size_t)(r0 + 1) * PIX + pc);

    float acc0[NCLS] = {}, acc1[NCLS] = {};
#pragma unroll
    for (int i = 0; i < KC / 512; ++i) {             // 2 iterations
        const int e8 = i * 64 + lane;                // 8-pixel group index
        uint4 awq[NCLS];
#pragma unroll
        for (int k = 0; k < NCLS; ++k)
            awq[k] = *(const uint4*)(AwT + (size_t)k * PIX + pc + e8 * 8);
        const float4 va0 = xa[e8 * 2], va1 = xa[e8 * 2 + 1];
        const float4 vb0 = xb[e8 * 2], vb1 = xb[e8 * 2 + 1];
        const half2_t a01 = __builtin_amdgcn_cvt_pkrtz(va0.x, va0.y);
        const half2_t a23 = __builtin_amdgcn_cvt_pkrtz(va0.z, va0.w);
        const half2_t a45 = __builtin_amdgcn_cvt_pkrtz(va1.x, va1.y);
        const half2_t a67 = __builtin_amdgcn_cvt_pkrtz(va1.z, va1.w);
        const half2_t b01 = __builtin_amdgcn_cvt_pkrtz(vb0.x, vb0.y);
        const half2_t b23 = __builtin_amdgcn_cvt_pkrtz(vb0.z, vb0.w);
        const half2_t b45 = __builtin_amdgcn_cvt_pkrtz(vb1.x, vb1.y);
        const half2_t b67 = __builtin_amdgcn_cvt_pkrtz(vb1.z, vb1.w);
#pragma unroll
        for (int k = 0; k < NCLS; ++k) {
            const half2_t w01 = __builtin_bit_cast(half2_t, awq[k].x);
            const half2_t w23 = __builtin_bit_cast(half2_t, awq[k].y);
            const half2_t w45 = __builtin_bit_cast(half2_t, awq[k].z);
            const half2_t w67 = __builtin_bit_cast(half2_t, awq[k].w);
            acc0[k] = fdot2f(a67, w67, fdot2f(a45, w45,
                      fdot2f(a23, w23, fdot2f(a01, w01, acc0[k]))));
            acc1[k] = fdot2f(b67, w67, fdot2f(b45, w45,
                      fdot2f(b23, w23, fdot2f(b01, w01, acc1[k]))));
        }
    }

    // ---- reduce + atomics ----
#pragma unroll
    for (int k = 0; k < NCLS; ++k) {
        part[k * 264 + t]        = acc0[k];
        part[(10 + k) * 264 + t] = acc1[k];
    }
    __syncthreads();

    if (t < 80) {
        const int w2 = t / 20, j = t % 20;
        const float4* src = (const float4*)(part + j * 264 + w2 * 64);
        float4 s4 = src[0];
#pragma unroll
        for (int q = 1; q < 16; ++q) {
            const float4 v = src[q];
            s4.x += v.x; s4.y += v.y; s4.z += v.z; s4.w += v.w;
        }
        const float s = (s4.x + s4.y) + (s4.z + s4.w);
        const int r = j / 10, k = j % 10;
        unsafeAtomicAdd(&out[(rowg * 8 + w2 * 2 + r) * NCLS + k], s);
    }
}

// ---------------------------------------------------------------------------
extern "C" void kernel_launch(void* const* d_in, const int* in_sizes, int n_in,
                              void* d_out, int out_size, void* d_ws, size_t ws_size,
                              hipStream_t stream)
{
    const float* x     = (const float*)d_in[0];
    const float* W_fgl = (const float*)d_in[1];
    const float* b_fgl = (const float*)d_in[2];
    const float* W_fc  = (const float*)d_in[3];
    const float* b_fc  = (const float*)d_in[4];
    const int*   seg   = (const int*)d_in[5];
    float*       out   = (float*)d_out;

    unsigned* AwT32 = (unsigned*)d_ws;     // AwT [10][65536] f16 = 1.31 MB

    awbuild_kernel<<<dim3(256),        256, 0, stream>>>(
        W_fgl, b_fgl, W_fc, b_fc, seg, AwT32, out);

    gemm_kernel<<<dim3(NRG * NKC), 256, 0, stream>>>(
        x, (const unsigned short*)AwT32, out);
}